// Round 12
// baseline (2534.259 us; speedup 1.0000x reference)
//
#include <hip/hip_runtime.h>
#include <hip/hip_bf16.h>
#include <stdint.h>

#define B_ 128
#define T_ 512
#define D_ 1024
#define H_ 1024

typedef __attribute__((ext_vector_type(8))) short bf16x8;
typedef __attribute__((ext_vector_type(4))) float f32x4;
typedef unsigned int u32;
typedef __attribute__((ext_vector_type(4))) u32 u32x4;

__device__ __forceinline__ ushort f2bf(float f) {
  union { float f; uint32_t u; } v; v.f = f;
  uint32_t u = v.u + 0x7FFFu + ((v.u >> 16) & 1u);
  return (ushort)(u >> 16);
}
__device__ __forceinline__ float bf2f(ushort s) {
  union { uint32_t u; float f; } v; v.u = ((uint32_t)s) << 16;
  return v.f;
}

__device__ __forceinline__ void store_xp(float* p, float v) { *p = v; }
__device__ __forceinline__ void store_xp(ushort* p, float v) { *p = f2bf(v); }
__device__ __forceinline__ float load_xp(const float* p) { return *p; }
__device__ __forceinline__ float load_xp(const ushort* p) { return bf2f(*p); }

// ---------------- W_hh -> (hi, lo) bf16 split ----------------
__global__ void wsplit_kernel(const float* __restrict__ W,
                              ushort* __restrict__ hi, ushort* __restrict__ lo,
                              int n) {
  int i = blockIdx.x * blockDim.x + threadIdx.x;
  if (i < n) {
    float w = W[i];
    ushort h = f2bf(w);
    hi[i] = h;
    lo[i] = f2bf(w - bf2f(h));
  }
}

// ---------------- zero workspace region ----------------
__global__ void hzero_kernel(uint4* __restrict__ p, int n4) {
  int i = blockIdx.x * blockDim.x + threadIdx.x;
  if (i < n4) p[i] = make_uint4(0, 0, 0, 0);
}

// ---------------- xp = x @ W_ih^T + b_ih + b_hh, stored [T,B,H] ----------------
// Grid (8, 512): bn fastest -> the 8 N-tiles of one M-band co-resident, x
// streamed from HBM ~once. Staging converts fp32->bf16 via
// __float22bfloat162_rn (v_cvt_pk_bf16_f32, RTNE — value-identical to f2bf).
template <typename XPT>
__global__ __launch_bounds__(256) void xp_gemm(
    const float* __restrict__ x, const float* __restrict__ Wih,
    const float* __restrict__ bih, const float* __restrict__ bhh,
    XPT* __restrict__ xp) {
  __shared__ __align__(16) ushort As[128][40];
  __shared__ __align__(16) ushort Bs[128][40];
  const int tid = threadIdx.x;
  const int lane = tid & 63;
  const int w = tid >> 6;
  const int wm = w >> 1, wn = w & 1;
  const int bn = blockIdx.x;  // 8 N-tiles (fastest -> L2 reuse of x)
  const int bm = blockIdx.y;  // 512 M-tiles

  f32x4 acc[4][4] = {};

  for (int kt = 0; kt < D_ / 32; ++kt) {
    __syncthreads();
#pragma unroll
    for (int i = 0; i < 4; ++i) {
      int c = tid + i * 256;      // 0..1023
      int isB = c >> 9;           // 0: A chunk, 1: B chunk
      int cc = c & 511;
      int row = cc >> 2;          // 0..127
      int col8 = (cc & 3) << 3;   // 0,8,16,24
      const float* src = isB
          ? (Wih + (size_t)(bn * 128 + row) * D_ + kt * 32 + col8)
          : (x + (size_t)(bm * 128 + row) * D_ + kt * 32 + col8);
      float4 f0 = *(const float4*)(src);
      float4 f1 = *(const float4*)(src + 4);
      union { __hip_bfloat162 h2[4]; uint4 u; } pk;
      pk.h2[0] = __float22bfloat162_rn(make_float2(f0.x, f0.y));
      pk.h2[1] = __float22bfloat162_rn(make_float2(f0.z, f0.w));
      pk.h2[2] = __float22bfloat162_rn(make_float2(f1.x, f1.y));
      pk.h2[3] = __float22bfloat162_rn(make_float2(f1.z, f1.w));
      ushort* dst = isB ? &Bs[row][col8] : &As[row][col8];
      *(uint4*)dst = pk.u;
    }
    __syncthreads();

    bf16x8 af[4], bfr[4];
#pragma unroll
    for (int fm = 0; fm < 4; ++fm)
      af[fm] = *(const bf16x8*)&As[wm * 64 + fm * 16 + (lane & 15)][(lane >> 4) * 8];
#pragma unroll
    for (int fn = 0; fn < 4; ++fn)
      bfr[fn] = *(const bf16x8*)&Bs[wn * 64 + fn * 16 + (lane & 15)][(lane >> 4) * 8];
#pragma unroll
    for (int fm = 0; fm < 4; ++fm)
#pragma unroll
      for (int fn = 0; fn < 4; ++fn)
        acc[fm][fn] = __builtin_amdgcn_mfma_f32_16x16x32_bf16(
            af[fm], bfr[fn], acc[fm][fn], 0, 0, 0);
  }

  float bias[4];
#pragma unroll
  for (int fn = 0; fn < 4; ++fn) {
    int j = bn * 128 + wn * 64 + fn * 16 + (lane & 15);
    bias[fn] = bih[j] + bhh[j];
  }
#pragma unroll
  for (int fm = 0; fm < 4; ++fm) {
#pragma unroll
    for (int r = 0; r < 4; ++r) {
      int m = bm * 128 + wm * 64 + fm * 16 + ((lane >> 4) * 4) + r;
      int t = m & (T_ - 1);
      int b = m >> 9;  // m / T_
      size_t base = (size_t)t * (B_ * H_) + (size_t)b * H_;
#pragma unroll
      for (int fn = 0; fn < 4; ++fn) {
        int j = bn * 128 + wn * 64 + fn * 16 + (lane & 15);
        store_xp(xp + base + j, acc[fm][fn][r] + bias[fn]);
      }
    }
  }
}

// ---------------- persistent recurrence v10: direct fragment gather ----------------
// 256 WGs: replica = bid&7 (16 batches), wgc = bid>>3 (32 cols). Wave = K-quarter.
// h kept as SEPARATE hi/lo bf16 planes -> each lane loads its MFMA A-fragments
// DIRECTLY (16B at row r16, col ks*32+kg*8): the 4 kg-lanes cover exactly one
// 64B line per row -> fully dense, no LDS restage, no perm unpack, no bank
// conflicts. Sync = round-11 proven: plain agent-store posts (slot kq), per-wave
// producer poll, one barrier; WAR invariant unchanged.
template <typename XPT>
__global__ __launch_bounds__(256, 1) void rnn_persist(
    const ushort* __restrict__ Whi, const ushort* __restrict__ Wlo,
    const XPT* __restrict__ xp,
    ushort* __restrict__ hh,   // [2][B_][H_] hi plane
    ushort* __restrict__ hl,   // [2][B_][H_] lo plane
    u32* __restrict__ cnt,     // [256][16]: line (rep*32+wgc), slots 0..3 = waves
    float* __restrict__ out) {
  __shared__ __align__(16) f32x4 red[2][4][2][64];       // 16 KB

  const int bid = blockIdx.x;
  const int rep = bid & 7;    // batches [rep*16, rep*16+16)
  const int wgc = bid >> 3;   // cols [wgc*32, wgc*32+32)
  const int tid = threadIdx.x;
  const int lane = tid & 63;
  const int kq = tid >> 6;    // wave = K-quarter
  const int r16 = lane & 15;
  const int kg = lane >> 4;   // 0..3
  const int nf_e = kq & 1;    // epilogue: nf slice
  const int rh_e = kq >> 1;   // epilogue: row pair
  const int l5 = lane & 31;

  // ---- preload W fragments into registers (128 VGPR) ----
  bf16x8 wbh[8][2], wbl[8][2];
#pragma unroll
  for (int ks = 0; ks < 8; ++ks) {
#pragma unroll
    for (int nf = 0; nf < 2; ++nf) {
      int col = wgc * 32 + nf * 16 + r16;
      int k = kq * 256 + ks * 32 + kg * 8;
      wbh[ks][nf] = *(const bf16x8*)(Whi + (size_t)col * H_ + k);
      wbl[ks][nf] = *(const bf16x8*)(Wlo + (size_t)col * H_ + k);
    }
  }

  const int erow0 = rep * 16 + kg * 4 + rh_e * 2;
  const int ecol = wgc * 32 + nf_e * 16 + r16;
  u32* mypost = cnt + (size_t)(rep * 32 + wgc) * 16 + kq;
  const u32* mypoll = cnt + (size_t)(rep * 32 + kq * 8 + (l5 >> 2)) * 16 + (l5 & 3);
  // fragment base: row (rep*16 + r16), k = kq*256 + kg*8 (+ks*32)
  const size_t fb = (size_t)(rep * 16 + r16) * H_ + kq * 256 + kg * 8;

  for (int t = 0; t < T_; ++t) {
    const ushort* Hh = hh + (size_t)(t & 1) * (B_ * H_);
    const ushort* Hl = hl + (size_t)(t & 1) * (B_ * H_);
    ushort* Hhn = hh + (size_t)((t + 1) & 1) * (B_ * H_);
    ushort* Hln = hl + (size_t)((t + 1) & 1) * (B_ * H_);

    // ---- per-wave poll: my quarter's 8 producer WGs x 4 wave-slots >= t ----
    if (t) {
      const u32 target = (u32)t;
      for (;;) {
        u32 v = __hip_atomic_load(mypoll, __ATOMIC_RELAXED, __HIP_MEMORY_SCOPE_AGENT);
        if (__all((int)(v >= target))) break;
        __builtin_amdgcn_s_sleep(1);
      }
    }

    // xp prefetch (plain cached loads)
    float xpv[2];
#pragma unroll
    for (int e = 0; e < 2; ++e)
      xpv[e] = load_xp(xp + (size_t)t * (B_ * H_) + (size_t)(erow0 + e) * H_ + ecol);

    // ---- direct fragment gather: 8 hi + 8 lo dwordx4 per lane ----
    u32x4 ah[8], al[8];
#pragma unroll
    for (int ks = 0; ks < 8; ++ks) {
      const ushort* ph = Hh + fb + ks * 32;
      const ushort* pl = Hl + fb + ks * 32;
      asm volatile("global_load_dwordx4 %0, %1, off sc0 sc1"
                   : "=&v"(ah[ks]) : "v"(ph) : "memory");
      asm volatile("global_load_dwordx4 %0, %1, off sc0 sc1"
                   : "=&v"(al[ks]) : "v"(pl) : "memory");
    }
    asm volatile("s_waitcnt vmcnt(0)" ::: "memory");
    __builtin_amdgcn_sched_barrier(0);

    // ---- MFMA (A frags straight from registers) ----
    f32x4 acc[2] = {};
#pragma unroll
    for (int ks = 0; ks < 8; ++ks) {
      union { u32x4 u; bf16x8 v; } cah, cal;
      cah.u = ah[ks]; cal.u = al[ks];
#pragma unroll
      for (int nf = 0; nf < 2; ++nf) {
        acc[nf] = __builtin_amdgcn_mfma_f32_16x16x32_bf16(cah.v, wbh[ks][nf], acc[nf], 0, 0, 0);
        acc[nf] = __builtin_amdgcn_mfma_f32_16x16x32_bf16(cal.v, wbh[ks][nf], acc[nf], 0, 0, 0);
        acc[nf] = __builtin_amdgcn_mfma_f32_16x16x32_bf16(cah.v, wbl[ks][nf], acc[nf], 0, 0, 0);
      }
    }

    // ---- all-to-all K reduce (parity double-buffered, one barrier) ----
    const int par = t & 1;
    red[par][kq][0][lane] = acc[0];
    red[par][kq][1][lane] = acc[1];
    __syncthreads();   // joins 4 waves => all 32 producers done (WAR safety)

    // ---- parallel epilogue: vector red reads + uniform select ----
    {
      f32x4 sum = red[par][0][nf_e][lane];
      sum += red[par][1][nf_e][lane];
      sum += red[par][2][nf_e][lane];
      sum += red[par][3][nf_e][lane];
      float s0 = rh_e ? sum[2] : sum[0];
      float s1 = rh_e ? sum[3] : sum[1];
      float h0 = tanhf(s0 + xpv[0]);
      float h1 = tanhf(s1 + xpv[1]);
      ushort hb0 = f2bf(h0), hb1 = f2bf(h1);
      ushort lb0 = f2bf(h0 - bf2f(hb0));
      ushort lb1 = f2bf(h1 - bf2f(hb1));
      ushort* dh0 = Hhn + (size_t)erow0 * H_ + ecol;
      ushort* dh1 = Hhn + (size_t)(erow0 + 1) * H_ + ecol;
      ushort* dl0 = Hln + (size_t)erow0 * H_ + ecol;
      ushort* dl1 = Hln + (size_t)(erow0 + 1) * H_ + ecol;
      asm volatile("global_store_short %0, %1, off sc0 sc1" :: "v"(dh0), "v"((u32)hb0) : "memory");
      asm volatile("global_store_short %0, %1, off sc0 sc1" :: "v"(dh1), "v"((u32)hb1) : "memory");
      asm volatile("global_store_short %0, %1, off sc0 sc1" :: "v"(dl0), "v"((u32)lb0) : "memory");
      asm volatile("global_store_short %0, %1, off sc0 sc1" :: "v"(dl1), "v"((u32)lb1) : "memory");
      if (t == T_ - 1) {
        out[(size_t)erow0 * H_ + ecol] = h0;
        out[(size_t)(erow0 + 1) * H_ + ecol] = h1;
      }
    }

    // ---- completion: drain stores, post own wave slot (plain agent store) ----
    asm volatile("s_waitcnt vmcnt(0)" ::: "memory");
    __builtin_amdgcn_sched_barrier(0);
    if (lane == 0)
      __hip_atomic_store(mypost, (u32)(t + 1),
                         __ATOMIC_RELAXED, __HIP_MEMORY_SCOPE_AGENT);
  }
}

// ---------------- launch ----------------
extern "C" void kernel_launch(void* const* d_in, const int* in_sizes, int n_in,
                              void* d_out, int out_size, void* d_ws, size_t ws_size,
                              hipStream_t stream) {
  const float* x    = (const float*)d_in[0];
  const float* W_ih = (const float*)d_in[1];
  const float* W_hh = (const float*)d_in[2];
  const float* b_ih = (const float*)d_in[3];
  const float* b_hh = (const float*)d_in[4];
  float* out = (float*)d_out;

  const size_t xp_f32_bytes = (size_t)T_ * B_ * H_ * 4;   // 256 MB
  const size_t xp_bf_bytes  = xp_f32_bytes / 2;           // 128 MB
  const size_t wsp_bytes    = 2 * (size_t)H_ * H_ * 2;    // 4 MB (hi+lo)
  const size_t hpl_bytes    = 4 * (size_t)B_ * H_ * 2;    // 1 MB (hi,lo x 2 bufs)
  const size_t cnt_bytes    = 256 * 64;                   // 16 KB

  bool fp32xp = ws_size >= xp_f32_bytes + wsp_bytes + hpl_bytes + cnt_bytes;
  bool bf16xp = !fp32xp && ws_size >= xp_bf_bytes + wsp_bytes + hpl_bytes + cnt_bytes;
  if (!fp32xp && !bf16xp) return;

  char* p = (char*)d_ws;
  size_t xp_bytes = fp32xp ? xp_f32_bytes : xp_bf_bytes;
  char* xp_raw = p;                       p += xp_bytes;
  ushort* Whi = (ushort*)p;               p += (size_t)H_ * H_ * 2;
  ushort* Wlo = (ushort*)p;               p += (size_t)H_ * H_ * 2;
  ushort* hh = (ushort*)p;                p += 2 * (size_t)B_ * H_ * 2;
  ushort* hl = (ushort*)p;                p += 2 * (size_t)B_ * H_ * 2;
  u32* cnt = (u32*)p;

  // 1) split W_hh
  {
    int n = H_ * H_;
    wsplit_kernel<<<(n + 255) / 256, 256, 0, stream>>>(W_hh, Whi, Wlo, n);
  }
  // 2) zero h planes + counters (contiguous; re-done every launch)
  {
    int n4 = (int)((hpl_bytes + cnt_bytes) / 16);
    hzero_kernel<<<(n4 + 255) / 256, 256, 0, stream>>>((uint4*)hh, n4);
  }
  // 3) xp GEMM — transposed grid: bn fastest so x is read from HBM ~once
  dim3 gxp(8, 512);
  if (fp32xp)
    xp_gemm<float><<<gxp, 256, 0, stream>>>(x, W_ih, b_ih, b_hh, (float*)xp_raw);
  else
    xp_gemm<ushort><<<gxp, 256, 0, stream>>>(x, W_ih, b_ih, b_hh, (ushort*)xp_raw);

  // 4) persistent recurrence (256 WGs, 1 WG/CU)
  if (fp32xp)
    rnn_persist<float><<<256, 256, 0, stream>>>(Whi, Wlo, (const float*)xp_raw,
                                                hh, hl, cnt, out);
  else
    rnn_persist<ushort><<<256, 256, 0, stream>>>(Whi, Wlo, (const ushort*)xp_raw,
                                                 hh, hl, cnt, out);
}